// Round 8
// baseline (1532.037 us; speedup 1.0000x reference)
//
#include <hip/hip_runtime.h>
#include <hip/hip_bf16.h>

#define N_ATOMS 25000
#define N_PAIRS 500000
#define DEPTH 4
#define TILE 192
#define PTHREADS 768
#define SENT 0x7fffffff

typedef _Float16 f16x8 __attribute__((ext_vector_type(8)));
typedef float f32x16 __attribute__((ext_vector_type(16)));
typedef unsigned short u16;
typedef unsigned int u32;

__device__ __forceinline__ float tanh_fast(float x) {
    // tanh(x) = 1 - 2/(exp(2x)+1); saturates correctly at +/-inf
    float e = __expf(2.0f * x);
    return 1.0f - 2.0f * __builtin_amdgcn_rcpf(e + 1.0f);
}

__device__ __forceinline__ void split_h(float x, u16& hi, u16& lo) {
    _Float16 h = (_Float16)x;                 // RNE
    _Float16 l = (_Float16)(x - (float)h);    // residual, RNE
    hi = *(u16*)&h;
    lo = *(u16*)&l;
}

// LDS bank-swizzle on 16B-unit index (involution within 128B block).
// Verified: SQ_LDS_BANK_CONFLICT 2.02e7 -> 0 (rounds 1-3).
__device__ __forceinline__ int swz8(int u) { return u ^ ((u >> 5) & 7); }

// ---------------- prep: split weights to hi/lo fp16, fragment-major images
__global__ __launch_bounds__(256)
void prep_kernel(const float* __restrict__ piW1, const float* __restrict__ piW2,
                 const float* __restrict__ iiW1, const float* __restrict__ iiW2,
                 u16* __restrict__ img1, u16* __restrict__ img2, u16* __restrict__ imgab) {
    int gid = blockIdx.x * 256 + threadIdx.x;
    int d = gid >> 15, e = gid & 32767;
    u16 hi, lo;
    if (e < 8192) {                 // W1 [k=128][n=64] (unused by pair since R5)
        int k = e >> 6, n = e & 63;
        split_h(piW1[d * 8192 + e], hi, lo);
        int ntw = n >> 5, colb = n & 31;
        int ks = k >> 4, lh = (k >> 3) & 1, j = k & 7;
        int off = ((ntw * 8 + ks) * 64 + lh * 32 + colb) * 8 + j;
        img1[d * 16384 + 0 * 8192 + off] = hi;
        img1[d * 16384 + 1 * 8192 + off] = lo;
    } else if (e < 24576) {         // W2 [k=64][n=256], permuted n = 4*ch + t
        int s = e - 8192;
        int k = s >> 8, n = s & 255;
        split_h(piW2[d * 16384 + s], hi, lo);
        int ch = n >> 2, t = n & 3;
        int ntw = ch >> 5, colb = ch & 31;
        int ks = k >> 4, lh = (k >> 3) & 1, j = k & 7;
        int off = (((ntw * 4 + t) * 4 + ks) * 64 + lh * 32 + colb) * 8 + j;
        img2[d * 32768 + 0 * 16384 + off] = hi;
        img2[d * 32768 + 1 * 16384 + off] = lo;
    } else {                        // Wa (stage0) / Wb (stage1), [k=64][n=64]
        int stage = (e < 28672) ? 0 : 1;
        int s = e - (stage ? 28672 : 24576);
        int k = s >> 6, n = s & 63;
        float x = stage ? iiW2[d * 4096 + s] : iiW1[d * 4096 + s];
        split_h(x, hi, lo);
        int ntw = n >> 5, colb = n & 31;
        int ks = k >> 4, lh = (k >> 3) & 1, j = k & 7;
        int off = ((ntw * 4 + ks) * 64 + lh * 32 + colb) * 8 + j;
        imgab[d * 16384 + (stage * 2 + 0) * 4096 + off] = hi;
        imgab[d * 16384 + (stage * 2 + 1) * 4096 + off] = lo;
    }
}

__global__ __launch_bounds__(256)
void prep_b2(const float* __restrict__ piB2, float* __restrict__ b2p) {
    int d = blockIdx.x, n = threadIdx.x;
    int ch = n >> 2, t = n & 3;
    int np = (ch >> 5) * 128 + t * 32 + (ch & 31);
    b2p[d * 256 + np] = piB2[d * 256 + n];
}

// ---------------- counting sort of pairs by ind_i (once per launch; reused all depths)
__global__ __launch_bounds__(256)
void zero_hist(u32* __restrict__ hist) {
    int i = blockIdx.x * 256 + threadIdx.x;
    if (i < 25024) hist[i] = 0u;
}

__global__ __launch_bounds__(256)
void hist_kernel(const int* __restrict__ ind2, u32* __restrict__ hist) {
    int p = blockIdx.x * 256 + threadIdx.x;
    if (p < N_PAIRS) atomicAdd(&hist[ind2[2 * p]], 1u);
}

// multi-block scan: local exclusive scans + block totals
__global__ __launch_bounds__(256)
void scan_local(const u32* __restrict__ hist, u32* __restrict__ cursor,
                u32* __restrict__ blockSum) {
    __shared__ u32 sd[256];
    int t = threadIdx.x, b = blockIdx.x;
    int idx = b * 256 + t;
    u32 v = (idx < N_ATOMS) ? hist[idx] : 0u;
    sd[t] = v;
    __syncthreads();
    for (int off = 1; off < 256; off <<= 1) {
        u32 x = (t >= off) ? sd[t - off] : 0u;
        __syncthreads();
        sd[t] += x;
        __syncthreads();
    }
    if (idx < N_ATOMS) cursor[idx] = sd[t] - v;   // local exclusive
    if (t == 255) blockSum[b] = sd[255];
}

__global__ __launch_bounds__(128)
void scan_tops(const u32* __restrict__ blockSum, u32* __restrict__ blockOff) {
    __shared__ u32 sd[128];
    int t = threadIdx.x;
    u32 v = (t < 98) ? blockSum[t] : 0u;
    sd[t] = v;
    __syncthreads();
    for (int off = 1; off < 128; off <<= 1) {
        u32 x = (t >= off) ? sd[t - off] : 0u;
        __syncthreads();
        sd[t] += x;
        __syncthreads();
    }
    if (t < 98) blockOff[t] = sd[t] - v;          // exclusive
}

__global__ __launch_bounds__(256)
void scan_add(u32* __restrict__ cursor, const u32* __restrict__ blockOff) {
    int idx = blockIdx.x * 256 + threadIdx.x;
    if (idx < N_ATOMS) cursor[idx] += blockOff[blockIdx.x];
}

__global__ __launch_bounds__(256)
void scatter_kernel(const int* __restrict__ ind2, const float* __restrict__ basis,
                    u32* __restrict__ cursor, int2* __restrict__ sIJ,
                    float4* __restrict__ sBas4) {
    int p = blockIdx.x * 256 + threadIdx.x;
    if (p >= N_PAIRS) return;
    int i = ind2[2 * p], j = ind2[2 * p + 1];
    u32 pos = atomicAdd(&cursor[i], 1u);
    sIJ[pos] = make_int2(i, j);
    sBas4[pos] = ((const float4*)basis)[p];
}

// ---------------- atom-level MLP (R5 version: 4 atoms/block, no spill); emits U,V
template <int K, bool IS_D0>
__global__ __launch_bounds__(256)
void atom_mlp(const float* __restrict__ p_in,
              const float* __restrict__ W1, const float* __restrict__ b1,
              const float* __restrict__ W2, const float* __restrict__ b2,
              const float* __restrict__ res0_w,
              const float* __restrict__ piW1d,
              float* __restrict__ Uo, float* __restrict__ Vo,
              float* __restrict__ acc_out) {
    __shared__ float sP[4][64];
    __shared__ float sH[4][64];
    __shared__ float sH2[4][64];
    int tid = threadIdx.x;
    int al = tid >> 6, c = tid & 63;
    int a = blockIdx.x * 4 + al;
    if (c < K) sP[al][c] = p_in[a * K + c];
    __syncthreads();
    float s = b1[c];
#pragma unroll
    for (int k = 0; k < K; ++k) s += sP[al][k] * W1[k * 64 + c];
    float t1 = tanh_fast(s);
    float r;
    if (IS_D0) {
        r = 0.f;
#pragma unroll
        for (int k = 0; k < 16; ++k) r += sP[al][k] * res0_w[k * 64 + c];
    } else {
        r = sP[al][c];
    }
    acc_out[a * 64 + c] = r;
    sH[al][c] = t1;
    __syncthreads();
    float s2 = b2[c];
#pragma unroll
    for (int k = 0; k < 64; ++k) s2 += sH[al][k] * W2[k * 64 + c];
    float hv = tanh_fast(s2);
    sH2[al][c] = hv;
    __syncthreads();
    float su = 0.f, sv = 0.f;
#pragma unroll
    for (int k = 0; k < 64; ++k) {
        float x = sH2[al][k];
        su += x * piW1d[k * 64 + c];
        sv += x * piW1d[(64 + k) * 64 + c];
    }
    Uo[a * 64 + c] = su;
    Vo[a * 64 + c] = sv;
}

// ---------------- output head (fp32), standalone (after last depth)
__global__ __launch_bounds__(256)
void out_kernel(const float* __restrict__ p,
                const float* __restrict__ W1, const float* __restrict__ b1,
                const float* __restrict__ W2, const float* __restrict__ b2,
                const float* __restrict__ wo,
                float* __restrict__ out, int store) {
    __shared__ float sP[4][64];
    __shared__ float sH[4][64];
    int tid = threadIdx.x;
    int al = tid >> 6, c = tid & 63;
    int a = blockIdx.x * 4 + al;
    sP[al][c] = p[a * 64 + c];
    __syncthreads();
    float s = b1[c];
#pragma unroll
    for (int k = 0; k < 64; ++k) s += sP[al][k] * W1[k * 64 + c];
    sH[al][c] = tanh_fast(s);
    __syncthreads();
    float s2 = b2[c];
#pragma unroll
    for (int k = 0; k < 64; ++k) s2 += sH[al][k] * W2[k * 64 + c];
    float v = tanh_fast(s2) * wo[c];
#pragma unroll
    for (int off = 32; off > 0; off >>= 1) v += __shfl_down(v, off, 64);
    if (c == 0) {
        if (store) out[a] = v;
        else out[a] += v;
    }
}

// ---------------- fused: out head of depth d + atom MLP of depth d+1 (+U/V)
__global__ __launch_bounds__(256)
void fused_out_atom(const float* __restrict__ p,
                    const float* __restrict__ oW1, const float* __restrict__ ob1,
                    const float* __restrict__ oW2, const float* __restrict__ ob2,
                    const float* __restrict__ wo,
                    const float* __restrict__ aW1, const float* __restrict__ ab1,
                    const float* __restrict__ aW2, const float* __restrict__ ab2,
                    float* __restrict__ out, int store,
                    const float* __restrict__ piW1d,
                    float* __restrict__ Uo, float* __restrict__ Vo,
                    float* __restrict__ acc_out) {
    __shared__ float sP[4][64];
    __shared__ float sHo[4][64];
    __shared__ float sHa[4][64];
    int tid = threadIdx.x;
    int al = tid >> 6, c = tid & 63;
    int a = blockIdx.x * 4 + al;
    float pv = p[a * 64 + c];
    sP[al][c] = pv;
    acc_out[a * 64 + c] = pv;            // residual base for next depth
    __syncthreads();
    float so = ob1[c], sa = ab1[c];
#pragma unroll
    for (int k = 0; k < 64; ++k) {
        float x = sP[al][k];
        so += x * oW1[k * 64 + c];
        sa += x * aW1[k * 64 + c];
    }
    sHo[al][c] = tanh_fast(so);
    sHa[al][c] = tanh_fast(sa);
    __syncthreads();
    float s2o = ob2[c], s2a = ab2[c];
#pragma unroll
    for (int k = 0; k < 64; ++k) {
        s2o += sHo[al][k] * oW2[k * 64 + c];
        s2a += sHa[al][k] * aW2[k * 64 + c];
    }
    float v = tanh_fast(s2o) * wo[c];
#pragma unroll
    for (int off = 32; off > 0; off >>= 1) v += __shfl_down(v, off, 64);
    if (c == 0) {
        if (store) out[a] = v;
        else out[a] += v;
    }
    float hv = tanh_fast(s2a);
    sP[al][c] = hv;                      // sP dead after loop1; reuse for h
    __syncthreads();
    float su = 0.f, sv = 0.f;
#pragma unroll
    for (int k = 0; k < 64; ++k) {
        float x = sP[al][k];
        su += x * piW1d[k * 64 + c];
        sv += x * piW1d[(64 + k) * 64 + c];
    }
    Uo[a * 64 + c] = su;
    Vo[a * 64 + c] = sv;
}

// ---------------- pair pipeline v4: sorted pairs, segment-reduced scatter,
// ii_w1/ii_w2 in registers (16 frags; VGPR 84->~150, LDS -32KB, -16 ds_read/wave/tile)
#define MFMA __builtin_amdgcn_mfma_f32_32x32x16_f16

__global__ __launch_bounds__(PTHREADS, 3)
void pair_kernel(const float* __restrict__ Uin,
                 const float* __restrict__ Vin,
                 const int2* __restrict__ sIJ,
                 const float4* __restrict__ sBas4,
                 const u16* __restrict__ img2,
                 const u16* __restrict__ imgab,
                 const float* __restrict__ piB1,
                 const float* __restrict__ b2p,
                 float* __restrict__ accp) {
    __shared__ __attribute__((aligned(16))) _Float16 sW2[32768];   // 64 KB
    __shared__ __attribute__((aligned(16))) _Float16 bufs[24576];  // 48 KB: bufA|bufB, fval f32 view
    __shared__ float sBas[TILE * 4];                               //  3 KB
    __shared__ int sIdx[TILE];                                     // 0.75 KB
    __shared__ unsigned short leadRow[TILE];                       // 0.38 KB
    __shared__ int nLead;
    // total ~116 KB -> 1 block/CU, 12 waves = 3 waves/SIMD

    const int tid = threadIdx.x;
    for (int i = tid; i < 4096; i += PTHREADS) ((uint4*)sW2)[i] = ((const uint4*)img2)[i];

    char* bufA = (char*)bufs;
    char* bufB = (char*)bufs + 24576;
    float* fval = (float*)bufs;            // [192][64] rotated: fval[r*64 + ((ch+r)&63)]

    const int l = tid & 63;
    const int w = tid >> 6;
    const int mt = w >> 1, ntw = w & 1;
    const int col = l & 31, kg = l >> 5;
    const int ch = ntw * 32 + col;
    const int chks = ch >> 4, chlh = (ch >> 3) & 1, chj = ch & 7;

    int rb[4], wb[4];
    {
        const int wxor = 2 * chks + chlh;
#pragma unroll
        for (int c = 0; c < 4; ++c) {
            rb[c] = (l ^ (kg + 2 * c)) << 4;
            wb[c] = (mt * 4 + chks) * 1024 + chlh * 512 + ((((c) + 4 * kg) ^ wxor) << 4) + chj * 2;
        }
    }
    const int mts = mt << 12;

    const int m = tid >> 2, ksel = tid & 3;
    const int mtd = m >> 5, lrow = m & 31;
    const int u0 = (mtd * 4 + ksel) * 64 + lrow;
    const int wA0 = swz8(u0) * 16, wA1 = swz8(u0 + 32) * 16;

    // persistent register weights: ii_w1 / ii_w2 hi+lo (16 frags = 64 VGPR)
    f16x8 fa[2][4], fb[2][4];
#pragma unroll
    for (int hl = 0; hl < 2; ++hl)
#pragma unroll
        for (int ks = 0; ks < 4; ++ks) {
            fa[hl][ks] = *(const f16x8*)(imgab + (0 * 2 + hl) * 4096 + ntw * 2048 + ks * 512 + l * 8);
            fb[hl][ks] = *(const f16x8*)(imgab + (1 * 2 + hl) * 4096 + ntw * 2048 + ks * 512 + l * 8);
        }

    float b1p[16];
#pragma unroll
    for (int z = 0; z < 16; ++z) b1p[z] = piB1[ksel * 16 + z];
    float b2v[4];
#pragma unroll
    for (int t = 0; t < 4; ++t) b2v[t] = b2p[ntw * 128 + t * 32 + col];

    const int nTiles = (N_PAIRS + TILE - 1) / TILE;

    float ur[16], vr[16];
    auto loadUV = [&](int tile) {
        int p = tile * TILE + m;
        bool ok = (p < N_PAIRS);
        int2 ij = ok ? sIJ[p] : make_int2(0, 0);
        const float* up = Uin + ij.x * 64 + ksel * 16;
        const float* vp = Vin + ij.y * 64 + ksel * 16;
        float4 z4 = make_float4(0.f, 0.f, 0.f, 0.f);
#pragma unroll
        for (int q = 0; q < 4; ++q) {
            float4 a = ok ? *(const float4*)(up + q * 4) : z4;
            float4 b = ok ? *(const float4*)(vp + q * 4) : z4;
            ur[q * 4 + 0] = a.x; ur[q * 4 + 1] = a.y; ur[q * 4 + 2] = a.z; ur[q * 4 + 3] = a.w;
            vr[q * 4 + 0] = b.x; vr[q * 4 + 1] = b.y; vr[q * 4 + 2] = b.z; vr[q * 4 + 3] = b.w;
        }
    };
    loadUV(blockIdx.x);

    for (int tile = blockIdx.x; tile < nTiles; tile += gridDim.x) {
        const int base = tile * TILE;

        // ---- P1: stage basis/sorted-i; G1out = tanh(U[i]+V[j]+b1) -> bufA frags
        if (tid < TILE) {
            int p = base + tid;
            bool ok = p < N_PAIRS;
            float4 bv = ok ? sBas4[p] : make_float4(0.f, 0.f, 0.f, 0.f);
            *(float4*)&sBas[tid * 4] = bv;
            sIdx[tid] = ok ? sIJ[p].x : SENT;
        }
        if (tid == 255) nLead = 0;
        {
            f16x8 lo8, hi8;
#pragma unroll
            for (int z = 0; z < 8; ++z)
                lo8[z] = (_Float16)tanh_fast(ur[z] + vr[z] + b1p[z]);
#pragma unroll
            for (int z = 0; z < 8; ++z)
                hi8[z] = (_Float16)tanh_fast(ur[8 + z] + vr[8 + z] + b1p[8 + z]);
            *(f16x8*)(bufA + wA0) = lo8;
            *(f16x8*)(bufA + wA1) = hi8;
        }
        __syncthreads();

        // ---- P2: build segment-leader list; [192x64]@[64x256]+b2, tanh, basis contraction -> bufB
        if (tid < TILE) {
            int id = sIdx[tid];
            if (tid == 0 || id != sIdx[tid - 1]) {
                int k = atomicAdd(&nLead, 1);
                leadRow[k] = (unsigned short)tid;
            }
        }
        {
            f16x8 afr[4];
#pragma unroll
            for (int ks = 0; ks < 4; ++ks)
                afr[ks] = *(const f16x8*)(bufA + mts + ks * 1024 + rb[ks]);
            float s[16];
#pragma unroll
            for (int r = 0; r < 16; ++r) s[r] = 0.f;
#pragma unroll
            for (int pp = 0; pp < 2; ++pp) {
                f32x16 a0 = {}, a1 = {};
                const int t0 = 2 * pp, t1 = 2 * pp + 1;
#pragma unroll
                for (int ks = 0; ks < 4; ++ks) {
                    a0 = MFMA(afr[ks], *(const f16x8*)(sW2 + ((ntw * 4 + t0) * 4 + ks) * 512 + l * 8), a0, 0, 0, 0);
                    a0 = MFMA(afr[ks], *(const f16x8*)(sW2 + 16384 + ((ntw * 4 + t0) * 4 + ks) * 512 + l * 8), a0, 0, 0, 0);
                    a1 = MFMA(afr[ks], *(const f16x8*)(sW2 + ((ntw * 4 + t1) * 4 + ks) * 512 + l * 8), a1, 0, 0, 0);
                    a1 = MFMA(afr[ks], *(const f16x8*)(sW2 + 16384 + ((ntw * 4 + t1) * 4 + ks) * 512 + l * 8), a1, 0, 0, 0);
                }
#pragma unroll
                for (int r = 0; r < 16; ++r) {
                    int lr2 = (r & 3) + 8 * (r >> 2) + 4 * kg;
                    int row = mt * 32 + lr2;
                    float2 bb = *(const float2*)&sBas[row * 4 + 2 * pp];
                    s[r] += tanh_fast(a0[r] + b2v[t0]) * bb.x + tanh_fast(a1[r] + b2v[t1]) * bb.y;
                }
            }
#pragma unroll
            for (int r = 0; r < 16; ++r)
                *(u16*)(bufB + wb[r & 3] + ((r >> 2) << 7)) =
                    __builtin_bit_cast(u16, (_Float16)s[r]);
        }
        __syncthreads();

        // ---- P3: inter @ ii_w1 (hi+lo from registers), tanh -> bufA
        {
            f32x16 ah = {}, al2 = {};
#pragma unroll
            for (int ks = 0; ks < 4; ++ks) {
                f16x8 a = *(const f16x8*)(bufB + mts + ks * 1024 + rb[ks]);
                ah  = MFMA(a, fa[0][ks], ah, 0, 0, 0);
                al2 = MFMA(a, fa[1][ks], al2, 0, 0, 0);
            }
#pragma unroll
            for (int r = 0; r < 16; ++r)
                *(u16*)(bufA + wb[r & 3] + ((r >> 2) << 7)) =
                    __builtin_bit_cast(u16, (_Float16)tanh_fast(ah[r] + al2[r]));
        }
        __syncthreads();

        // ---- P4: @ ii_w2 (registers), tanh -> f32 LDS tile (rotated); prefetch next-tile U/V
        {
            f16x8 afr[4];
#pragma unroll
            for (int ks = 0; ks < 4; ++ks)
                afr[ks] = *(const f16x8*)(bufA + mts + ks * 1024 + rb[ks]);
            __syncthreads();               // bufs reused as fval below
            loadUV(tile + gridDim.x);
            f32x16 ah = {}, al2 = {};
#pragma unroll
            for (int ks = 0; ks < 4; ++ks) {
                ah  = MFMA(afr[ks], fb[0][ks], ah, 0, 0, 0);
                al2 = MFMA(afr[ks], fb[1][ks], al2, 0, 0, 0);
            }
#pragma unroll
            for (int r = 0; r < 16; ++r) {
                int lr2 = (r & 3) + 8 * (r >> 2) + 4 * kg;
                int row = mt * 32 + lr2;
                fval[row * 64 + ((ch + row) & 63)] = tanh_fast(ah[r] + al2[r]);
            }
        }
        __syncthreads();

        // ---- P5: segmented reduce over sorted-i runs; ONE atomic per (segment, ch)
        {
            int ch2 = tid & 63;
            for (int s = tid >> 6; s < nLead; s += 12) {
                int lr = leadRow[s];
                int id = sIdx[lr];
                if (id == SENT) continue;
                float sum = 0.f;
                int r = lr;
                do {
                    sum += fval[r * 64 + ((ch2 + r) & 63)];
                    ++r;
                } while (r < TILE && sIdx[r] == id);
                atomicAdd(&accp[id * 64 + ch2], sum);
            }
        }
        __syncthreads();
    }
}

extern "C" void kernel_launch(void* const* d_in, const int* in_sizes, int n_in,
                              void* d_out, int out_size, void* d_ws, size_t ws_size,
                              hipStream_t stream) {
    const int* ind2 = (const int*)d_in[0];
    const float* prop = (const float*)d_in[1];
    const float* basis = (const float*)d_in[2];
    const float* pp0_w1 = (const float*)d_in[3];
    const float* pp0_b1 = (const float*)d_in[4];
    const float* pp_w1 = (const float*)d_in[5];
    const float* pp_b1 = (const float*)d_in[6];
    const float* pp_w2 = (const float*)d_in[7];
    const float* pp_b2 = (const float*)d_in[8];
    const float* pi_w1 = (const float*)d_in[9];
    const float* pi_b1 = (const float*)d_in[10];
    const float* pi_w2 = (const float*)d_in[11];
    const float* pi_b2 = (const float*)d_in[12];
    const float* ii_w1 = (const float*)d_in[13];
    const float* ii_w2 = (const float*)d_in[14];
    const float* res0_w = (const float*)d_in[15];
    const float* out_w1 = (const float*)d_in[16];
    const float* out_b1 = (const float*)d_in[17];
    const float* out_w2 = (const float*)d_in[18];
    const float* out_b2 = (const float*)d_in[19];
    const float* out_wo = (const float*)d_in[20];
    float* out = (float*)d_out;

    // workspace layout
    float* B0 = (float*)d_ws;                            // 25000*64 f32
    float* B1 = B0 + N_ATOMS * 64;
    float* Ubuf = B1 + N_ATOMS * 64;
    float* Vbuf = Ubuf + N_ATOMS * 64;
    float4* sBas4 = (float4*)(Vbuf + N_ATOMS * 64);      // 500000 float4 (16B-aligned)
    int2* sIJ = (int2*)(sBas4 + N_PAIRS);                // 500000 int2
    u16* img1 = (u16*)(sIJ + N_PAIRS);                   // 4*16384 u16
    u16* img2 = img1 + 4 * 16384;                        // 4*32768 u16
    u16* imgab = img2 + 4 * 32768;                       // 4*16384 u16
    float* b2p = (float*)(imgab + 4 * 16384);            // 4*256 f32
    u32* hist = (u32*)(b2p + 1024);                      // 25024 u32
    u32* cursor = hist + 25024;                          // 25024 u32
    u32* blockSum = cursor + 25024;                      // 128 u32
    u32* blockOff = blockSum + 128;                      // 128 u32
    float* pbuf[2] = {B0, B1};

    // counting sort of pairs by ind_i (reused by all 4 depths)
    zero_hist<<<98, 256, 0, stream>>>(hist);
    hist_kernel<<<(N_PAIRS + 255) / 256, 256, 0, stream>>>(ind2, hist);
    scan_local<<<98, 256, 0, stream>>>(hist, cursor, blockSum);
    scan_tops<<<1, 128, 0, stream>>>(blockSum, blockOff);
    scan_add<<<98, 256, 0, stream>>>(cursor, blockOff);
    scatter_kernel<<<(N_PAIRS + 255) / 256, 256, 0, stream>>>(ind2, basis, cursor, sIJ, sBas4);

    prep_kernel<<<512, 256, 0, stream>>>(pi_w1, pi_w2, ii_w1, ii_w2, img1, img2, imgab);
    prep_b2<<<4, 256, 0, stream>>>(pi_b2, b2p);

    for (int d = 0; d < DEPTH; ++d) {
        float* acc = pbuf[d & 1];
        if (d == 0) {
            atom_mlp<16, true><<<N_ATOMS / 4, 256, 0, stream>>>(
                prop, pp0_w1, pp0_b1, pp_w2, pp_b2, res0_w,
                pi_w1, Ubuf, Vbuf, acc);
        } else {
            const float* pin = pbuf[(d - 1) & 1];
            fused_out_atom<<<N_ATOMS / 4, 256, 0, stream>>>(
                pin,
                out_w1 + (d - 1) * 4096, out_b1 + (d - 1) * 64,
                out_w2 + (d - 1) * 4096, out_b2 + (d - 1) * 64, out_wo + (d - 1) * 64,
                pp_w1 + (d - 1) * 4096, pp_b1 + (d - 1) * 64,
                pp_w2 + d * 4096, pp_b2 + d * 64,
                out, (d - 1) == 0 ? 1 : 0,
                pi_w1 + d * 8192, Ubuf, Vbuf, acc);
        }
        pair_kernel<<<256, PTHREADS, 0, stream>>>(
            Ubuf, Vbuf, sIJ, sBas4,
            img2 + d * 32768, imgab + d * 16384,
            pi_b1 + d * 64, b2p + d * 256, acc);
    }
    out_kernel<<<N_ATOMS / 4, 256, 0, stream>>>(
        pbuf[(DEPTH - 1) & 1], out_w1 + (DEPTH - 1) * 4096, out_b1 + (DEPTH - 1) * 64,
        out_w2 + (DEPTH - 1) * 4096, out_b2 + (DEPTH - 1) * 64, out_wo + (DEPTH - 1) * 64,
        out, 0);
}

// Round 9
// 1285.990 us; speedup vs baseline: 1.1913x; 1.1913x over previous
//
#include <hip/hip_runtime.h>
#include <hip/hip_bf16.h>

#define N_ATOMS 25000
#define N_PAIRS 500000
#define DEPTH 4

typedef _Float16 f16x8 __attribute__((ext_vector_type(8)));
typedef float f32x16 __attribute__((ext_vector_type(16)));
typedef unsigned short u16;
typedef unsigned int u32;

__device__ __forceinline__ float tanh_fast(float x) {
    float e = __expf(2.0f * x);
    return 1.0f - 2.0f * __builtin_amdgcn_rcpf(e + 1.0f);
}

__device__ __forceinline__ void split_h(float x, u16& hi, u16& lo) {
    _Float16 h = (_Float16)x;
    _Float16 l = (_Float16)(x - (float)h);
    hi = *(u16*)&h;
    lo = *(u16*)&l;
}

// LDS bank-swizzle on 16B-unit index (involution within 128B block).
// Verified: SQ_LDS_BANK_CONFLICT 2.02e7 -> 0 (rounds 1-3).
__device__ __forceinline__ int swz8(int u) { return u ^ ((u >> 5) & 7); }

// ---------------- prep: split weights to hi/lo fp16, fragment-major images
__global__ __launch_bounds__(256)
void prep_kernel(const float* __restrict__ piW1, const float* __restrict__ piW2,
                 const float* __restrict__ iiW1, const float* __restrict__ iiW2,
                 u16* __restrict__ img1, u16* __restrict__ img2, u16* __restrict__ imgab) {
    int gid = blockIdx.x * 256 + threadIdx.x;
    int d = gid >> 15, e = gid & 32767;
    u16 hi, lo;
    if (e < 8192) {                 // W1 (unused by pair since R5; kept)
        int k = e >> 6, n = e & 63;
        split_h(piW1[d * 8192 + e], hi, lo);
        int ntw = n >> 5, colb = n & 31;
        int ks = k >> 4, lh = (k >> 3) & 1, j = k & 7;
        int off = ((ntw * 8 + ks) * 64 + lh * 32 + colb) * 8 + j;
        img1[d * 16384 + 0 * 8192 + off] = hi;
        img1[d * 16384 + 1 * 8192 + off] = lo;
    } else if (e < 24576) {         // W2 [k=64][n=256], permuted n = 4*ch + t
        int s = e - 8192;
        int k = s >> 8, n = s & 255;
        split_h(piW2[d * 16384 + s], hi, lo);
        int ch = n >> 2, t = n & 3;
        int ntw = ch >> 5, colb = ch & 31;
        int ks = k >> 4, lh = (k >> 3) & 1, j = k & 7;
        int off = (((ntw * 4 + t) * 4 + ks) * 64 + lh * 32 + colb) * 8 + j;
        img2[d * 32768 + 0 * 16384 + off] = hi;
        img2[d * 32768 + 1 * 16384 + off] = lo;
    } else {                        // Wa / Wb, [k=64][n=64]
        int stage = (e < 28672) ? 0 : 1;
        int s = e - (stage ? 28672 : 24576);
        int k = s >> 6, n = s & 63;
        float x = stage ? iiW2[d * 4096 + s] : iiW1[d * 4096 + s];
        split_h(x, hi, lo);
        int ntw = n >> 5, colb = n & 31;
        int ks = k >> 4, lh = (k >> 3) & 1, j = k & 7;
        int off = ((ntw * 4 + ks) * 64 + lh * 32 + colb) * 8 + j;
        imgab[d * 16384 + (stage * 2 + 0) * 4096 + off] = hi;
        imgab[d * 16384 + (stage * 2 + 1) * 4096 + off] = lo;
    }
}

__global__ __launch_bounds__(256)
void prep_b2(const float* __restrict__ piB2, float* __restrict__ b2p) {
    int d = blockIdx.x, n = threadIdx.x;
    int ch = n >> 2, t = n & 3;
    int np = (ch >> 5) * 128 + t * 32 + (ch & 31);
    b2p[d * 256 + np] = piB2[d * 256 + n];
}

// ---------------- atom-level MLP (4 atoms/block, no spill); emits U,V
template <int K, bool IS_D0>
__global__ __launch_bounds__(256)
void atom_mlp(const float* __restrict__ p_in,
              const float* __restrict__ W1, const float* __restrict__ b1,
              const float* __restrict__ W2, const float* __restrict__ b2,
              const float* __restrict__ res0_w,
              const float* __restrict__ piW1d,
              float* __restrict__ Uo, float* __restrict__ Vo,
              float* __restrict__ acc_out) {
    __shared__ float sP[4][64];
    __shared__ float sH[4][64];
    __shared__ float sH2[4][64];
    int tid = threadIdx.x;
    int al = tid >> 6, c = tid & 63;
    int a = blockIdx.x * 4 + al;
    if (c < K) sP[al][c] = p_in[a * K + c];
    __syncthreads();
    float s = b1[c];
#pragma unroll
    for (int k = 0; k < K; ++k) s += sP[al][k] * W1[k * 64 + c];
    float t1 = tanh_fast(s);
    float r;
    if (IS_D0) {
        r = 0.f;
#pragma unroll
        for (int k = 0; k < 16; ++k) r += sP[al][k] * res0_w[k * 64 + c];
    } else {
        r = sP[al][c];
    }
    acc_out[a * 64 + c] = r;
    sH[al][c] = t1;
    __syncthreads();
    float s2 = b2[c];
#pragma unroll
    for (int k = 0; k < 64; ++k) s2 += sH[al][k] * W2[k * 64 + c];
    float hv = tanh_fast(s2);
    sH2[al][c] = hv;
    __syncthreads();
    float su = 0.f, sv = 0.f;
#pragma unroll
    for (int k = 0; k < 64; ++k) {
        float x = sH2[al][k];
        su += x * piW1d[k * 64 + c];
        sv += x * piW1d[(64 + k) * 64 + c];
    }
    Uo[a * 64 + c] = su;
    Vo[a * 64 + c] = sv;
}

// ---------------- output head (fp32), standalone (after last depth)
__global__ __launch_bounds__(256)
void out_kernel(const float* __restrict__ p,
                const float* __restrict__ W1, const float* __restrict__ b1,
                const float* __restrict__ W2, const float* __restrict__ b2,
                const float* __restrict__ wo,
                float* __restrict__ out, int store) {
    __shared__ float sP[4][64];
    __shared__ float sH[4][64];
    int tid = threadIdx.x;
    int al = tid >> 6, c = tid & 63;
    int a = blockIdx.x * 4 + al;
    sP[al][c] = p[a * 64 + c];
    __syncthreads();
    float s = b1[c];
#pragma unroll
    for (int k = 0; k < 64; ++k) s += sP[al][k] * W1[k * 64 + c];
    sH[al][c] = tanh_fast(s);
    __syncthreads();
    float s2 = b2[c];
#pragma unroll
    for (int k = 0; k < 64; ++k) s2 += sH[al][k] * W2[k * 64 + c];
    float v = tanh_fast(s2) * wo[c];
#pragma unroll
    for (int off = 32; off > 0; off >>= 1) v += __shfl_down(v, off, 64);
    if (c == 0) {
        if (store) out[a] = v;
        else out[a] += v;
    }
}

// ---------------- fused: out head of depth d + atom MLP of depth d+1 (+U/V)
__global__ __launch_bounds__(256)
void fused_out_atom(const float* __restrict__ p,
                    const float* __restrict__ oW1, const float* __restrict__ ob1,
                    const float* __restrict__ oW2, const float* __restrict__ ob2,
                    const float* __restrict__ wo,
                    const float* __restrict__ aW1, const float* __restrict__ ab1,
                    const float* __restrict__ aW2, const float* __restrict__ ab2,
                    float* __restrict__ out, int store,
                    const float* __restrict__ piW1d,
                    float* __restrict__ Uo, float* __restrict__ Vo,
                    float* __restrict__ acc_out) {
    __shared__ float sP[4][64];
    __shared__ float sHo[4][64];
    __shared__ float sHa[4][64];
    int tid = threadIdx.x;
    int al = tid >> 6, c = tid & 63;
    int a = blockIdx.x * 4 + al;
    float pv = p[a * 64 + c];
    sP[al][c] = pv;
    acc_out[a * 64 + c] = pv;            // residual base for next depth
    __syncthreads();
    float so = ob1[c], sa = ab1[c];
#pragma unroll
    for (int k = 0; k < 64; ++k) {
        float x = sP[al][k];
        so += x * oW1[k * 64 + c];
        sa += x * aW1[k * 64 + c];
    }
    sHo[al][c] = tanh_fast(so);
    sHa[al][c] = tanh_fast(sa);
    __syncthreads();
    float s2o = ob2[c], s2a = ab2[c];
#pragma unroll
    for (int k = 0; k < 64; ++k) {
        s2o += sHo[al][k] * oW2[k * 64 + c];
        s2a += sHa[al][k] * aW2[k * 64 + c];
    }
    float v = tanh_fast(s2o) * wo[c];
#pragma unroll
    for (int off = 32; off > 0; off >>= 1) v += __shfl_down(v, off, 64);
    if (c == 0) {
        if (store) out[a] = v;
        else out[a] += v;
    }
    float hv = tanh_fast(s2a);
    sP[al][c] = hv;
    __syncthreads();
    float su = 0.f, sv = 0.f;
#pragma unroll
    for (int k = 0; k < 64; ++k) {
        float x = sP[al][k];
        su += x * piW1d[k * 64 + c];
        sv += x * piW1d[(64 + k) * 64 + c];
    }
    Uo[a * 64 + c] = su;
    Vo[a * 64 + c] = sv;
}

// ---------------- pair pipeline v5: 2-tile software pipeline, 2 barriers/tile
// alpha = { P1(t+1) | P3(t) }, beta = { P2(t+1) | P4(t) }
#define MFMA __builtin_amdgcn_mfma_f32_32x32x16_f16

__global__ __launch_bounds__(512, 2)
void pair_kernel(const float* __restrict__ Uin,
                 const float* __restrict__ Vin,
                 const int* __restrict__ ind2,
                 const float* __restrict__ basis,
                 const u16* __restrict__ img2,
                 const u16* __restrict__ imgab,
                 const float* __restrict__ piB1,
                 const float* __restrict__ b2p,
                 float* __restrict__ accp) {
    __shared__ __attribute__((aligned(16))) _Float16 sW2[32768];  // 64 KB
    __shared__ __attribute__((aligned(16))) u16 sAB[16384];       // 32 KB ii_w1/ii_w2 frags
    __shared__ __attribute__((aligned(16))) _Float16 bufX[8192];  // 16 KB P1 out (t+1)
    __shared__ __attribute__((aligned(16))) _Float16 bufY[8192];  // 16 KB P2 out
    __shared__ __attribute__((aligned(16))) _Float16 bufZ[8192];  // 16 KB P3 out
    __shared__ float sBas[128 * 4];                               //  2 KB
    __shared__ int sIdx[2][128];                                  //  1 KB (double-buffered)
    // total ~147 KB -> 1 block/CU, 8 waves = 2 waves/SIMD

    const int tid = threadIdx.x;
    for (int i = tid; i < 4096; i += 512) ((uint4*)sW2)[i] = ((const uint4*)img2)[i];
    for (int i = tid; i < 2048; i += 512) ((uint4*)sAB)[i] = ((const uint4*)imgab)[i];

    const int l = tid & 63;
    const int w = tid >> 6;
    const int mt = w >> 1, ntw = w & 1;          // mt 0..3
    const int col = l & 31, kg = l >> 5;
    const int ch = ntw * 32 + col;
    const int chks = ch >> 4, chlh = (ch >> 3) & 1, chj = ch & 7;

    int rb[4], wb[4];
    {
        const int wxor = 2 * chks + chlh;
#pragma unroll
        for (int c = 0; c < 4; ++c) {
            rb[c] = (l ^ (kg + 2 * c)) << 4;
            wb[c] = (mt * 4 + chks) * 1024 + chlh * 512 + ((((c) + 4 * kg) ^ wxor) << 4) + chj * 2;
        }
    }
    const int mts = mt << 12;

    const int m = tid >> 2, ksel = tid & 3;      // m 0..127
    const int mtd = m >> 5, lrow = m & 31;
    const int u0 = (mtd * 4 + ksel) * 64 + lrow;
    const int wA0 = swz8(u0) * 16, wA1 = swz8(u0 + 32) * 16;

    float b1p[16];
#pragma unroll
    for (int z = 0; z < 16; ++z) b1p[z] = piB1[ksel * 16 + z];
    float b2v[4];
#pragma unroll
    for (int t = 0; t < 4; ++t) b2v[t] = b2p[ntw * 128 + t * 32 + col];

    const int nTiles = (N_PAIRS + 127) >> 7;
    const int G = gridDim.x;

    float ur[16], vr[16];
    auto loadUV = [&](int tile) {
        int p = (tile << 7) + m;
        bool ok = (p < N_PAIRS);
        int2 ij = ok ? ((const int2*)ind2)[p] : make_int2(0, 0);
        const float* up = Uin + ij.x * 64 + ksel * 16;
        const float* vp = Vin + ij.y * 64 + ksel * 16;
        float4 z4 = make_float4(0.f, 0.f, 0.f, 0.f);
#pragma unroll
        for (int q = 0; q < 4; ++q) {
            float4 a = ok ? *(const float4*)(up + q * 4) : z4;
            float4 b = ok ? *(const float4*)(vp + q * 4) : z4;
            ur[q * 4 + 0] = a.x; ur[q * 4 + 1] = a.y; ur[q * 4 + 2] = a.z; ur[q * 4 + 3] = a.w;
            vr[q * 4 + 0] = b.x; vr[q * 4 + 1] = b.y; vr[q * 4 + 2] = b.z; vr[q * 4 + 3] = b.w;
        }
    };
    auto stage_meta = [&](int tile, int s) {
        if (tid < 128) {
            int p = (tile << 7) + tid;
            bool ok = p < N_PAIRS;
            float4 bv = ok ? ((const float4*)basis)[p] : make_float4(0.f, 0.f, 0.f, 0.f);
            *(float4*)&sBas[tid * 4] = bv;
            sIdx[s][tid] = ok ? ind2[2 * p] : 0;
        }
    };
    auto P1 = [&]() {     // consumes ur/vr -> bufX frags
        f16x8 lo8, hi8;
#pragma unroll
        for (int z = 0; z < 8; ++z)
            lo8[z] = (_Float16)tanh_fast(ur[z] + vr[z] + b1p[z]);
#pragma unroll
        for (int z = 0; z < 8; ++z)
            hi8[z] = (_Float16)tanh_fast(ur[8 + z] + vr[8 + z] + b1p[8 + z]);
        *(f16x8*)((char*)bufX + wA0) = lo8;
        *(f16x8*)((char*)bufX + wA1) = hi8;
    };
    auto P2 = [&]() {     // bufX @ W2 + b2, tanh, basis contraction -> bufY
        f16x8 afr[4];
#pragma unroll
        for (int ks = 0; ks < 4; ++ks)
            afr[ks] = *(const f16x8*)((const char*)bufX + mts + ks * 1024 + rb[ks]);
        float s[16];
#pragma unroll
        for (int r = 0; r < 16; ++r) s[r] = 0.f;
#pragma unroll
        for (int pp = 0; pp < 2; ++pp) {
            f32x16 a0 = {}, a1 = {};
            const int t0 = 2 * pp, t1 = 2 * pp + 1;
#pragma unroll
            for (int ks = 0; ks < 4; ++ks) {
                a0 = MFMA(afr[ks], *(const f16x8*)(sW2 + ((ntw * 4 + t0) * 4 + ks) * 512 + l * 8), a0, 0, 0, 0);
                a0 = MFMA(afr[ks], *(const f16x8*)(sW2 + 16384 + ((ntw * 4 + t0) * 4 + ks) * 512 + l * 8), a0, 0, 0, 0);
                a1 = MFMA(afr[ks], *(const f16x8*)(sW2 + ((ntw * 4 + t1) * 4 + ks) * 512 + l * 8), a1, 0, 0, 0);
                a1 = MFMA(afr[ks], *(const f16x8*)(sW2 + 16384 + ((ntw * 4 + t1) * 4 + ks) * 512 + l * 8), a1, 0, 0, 0);
            }
#pragma unroll
            for (int r = 0; r < 16; ++r) {
                int lr2 = (r & 3) + 8 * (r >> 2) + 4 * kg;
                int row = mt * 32 + lr2;
                float2 bb = *(const float2*)&sBas[row * 4 + 2 * pp];
                s[r] += tanh_fast(a0[r] + b2v[t0]) * bb.x + tanh_fast(a1[r] + b2v[t1]) * bb.y;
            }
        }
#pragma unroll
        for (int r = 0; r < 16; ++r)
            *(u16*)((char*)bufY + wb[r & 3] + ((r >> 2) << 7)) =
                __builtin_bit_cast(u16, (_Float16)s[r]);
    };
    auto P3 = [&]() {     // bufY @ ii_w1 (hi+lo), tanh -> bufZ
        f32x16 ah = {}, al2 = {};
#pragma unroll
        for (int ks = 0; ks < 4; ++ks) {
            f16x8 a = *(const f16x8*)((const char*)bufY + mts + ks * 1024 + rb[ks]);
            ah  = MFMA(a, *(const f16x8*)(sAB + 0 * 4096 + ntw * 2048 + ks * 512 + l * 8), ah, 0, 0, 0);
            al2 = MFMA(a, *(const f16x8*)(sAB + 1 * 4096 + ntw * 2048 + ks * 512 + l * 8), al2, 0, 0, 0);
        }
#pragma unroll
        for (int r = 0; r < 16; ++r)
            *(u16*)((char*)bufZ + wb[r & 3] + ((r >> 2) << 7)) =
                __builtin_bit_cast(u16, (_Float16)tanh_fast(ah[r] + al2[r]));
    };
    auto P4 = [&](int tile, int s) {   // bufZ @ ii_w2, tanh, atomic scatter
        f16x8 afr[4];
#pragma unroll
        for (int ks = 0; ks < 4; ++ks)
            afr[ks] = *(const f16x8*)((const char*)bufZ + mts + ks * 1024 + rb[ks]);
        f32x16 ah = {}, al2 = {};
#pragma unroll
        for (int ks = 0; ks < 4; ++ks) {
            ah  = MFMA(afr[ks], *(const f16x8*)(sAB + 2 * 4096 + ntw * 2048 + ks * 512 + l * 8), ah, 0, 0, 0);
            al2 = MFMA(afr[ks], *(const f16x8*)(sAB + 3 * 4096 + ntw * 2048 + ks * 512 + l * 8), al2, 0, 0, 0);
        }
#pragma unroll
        for (int r = 0; r < 16; ++r) {
            int lr2 = (r & 3) + 8 * (r >> 2) + 4 * kg;
            int row = mt * 32 + lr2;
            int p = (tile << 7) + row;
            if (p < N_PAIRS)
                atomicAdd(&accp[sIdx[s][row] * 64 + ch], tanh_fast(ah[r] + al2[r]));
        }
    };

    // ---- pipeline prologue
    int t = blockIdx.x;
    int sb = 0;
    loadUV(t);
    stage_meta(t, sb);
    P1();                       // X(t)
    __syncthreads();
    loadUV(t + G);              // for P1(t+G) in first alpha
    P2();                       // Y(t)
    __syncthreads();

    // ---- steady state: alpha { P1(tn), P3(t) }, beta { P2(tn), P4(t) }
    for (;;) {
        int tn = t + G;
        bool hasN = tn < nTiles;
        if (hasN) { stage_meta(tn, sb ^ 1); P1(); }   // X(tn)
        P3();                                          // Z(t)
        __syncthreads();
        if (hasN) { loadUV(tn + G); P2(); }            // Y(tn); UV for tn+G
        P4(t, sb);                                     // atomics(t)
        __syncthreads();
        if (!hasN) break;
        t = tn; sb ^= 1;
    }
}

extern "C" void kernel_launch(void* const* d_in, const int* in_sizes, int n_in,
                              void* d_out, int out_size, void* d_ws, size_t ws_size,
                              hipStream_t stream) {
    const int* ind2 = (const int*)d_in[0];
    const float* prop = (const float*)d_in[1];
    const float* basis = (const float*)d_in[2];
    const float* pp0_w1 = (const float*)d_in[3];
    const float* pp0_b1 = (const float*)d_in[4];
    const float* pp_w1 = (const float*)d_in[5];
    const float* pp_b1 = (const float*)d_in[6];
    const float* pp_w2 = (const float*)d_in[7];
    const float* pp_b2 = (const float*)d_in[8];
    const float* pi_w1 = (const float*)d_in[9];
    const float* pi_b1 = (const float*)d_in[10];
    const float* pi_w2 = (const float*)d_in[11];
    const float* pi_b2 = (const float*)d_in[12];
    const float* ii_w1 = (const float*)d_in[13];
    const float* ii_w2 = (const float*)d_in[14];
    const float* res0_w = (const float*)d_in[15];
    const float* out_w1 = (const float*)d_in[16];
    const float* out_b1 = (const float*)d_in[17];
    const float* out_w2 = (const float*)d_in[18];
    const float* out_b2 = (const float*)d_in[19];
    const float* out_wo = (const float*)d_in[20];
    float* out = (float*)d_out;

    // workspace layout
    float* B0 = (float*)d_ws;                            // 25000*64 f32
    float* B1 = B0 + N_ATOMS * 64;
    float* Ubuf = B1 + N_ATOMS * 64;
    float* Vbuf = Ubuf + N_ATOMS * 64;
    u16* img1 = (u16*)(Vbuf + N_ATOMS * 64);             // 4*16384 u16
    u16* img2 = img1 + 4 * 16384;                        // 4*32768 u16
    u16* imgab = img2 + 4 * 32768;                       // 4*16384 u16
    float* b2p = (float*)(imgab + 4 * 16384);            // 4*256 f32
    float* pbuf[2] = {B0, B1};

    prep_kernel<<<512, 256, 0, stream>>>(pi_w1, pi_w2, ii_w1, ii_w2, img1, img2, imgab);
    prep_b2<<<4, 256, 0, stream>>>(pi_b2, b2p);

    for (int d = 0; d < DEPTH; ++d) {
        float* acc = pbuf[d & 1];
        if (d == 0) {
            atom_mlp<16, true><<<N_ATOMS / 4, 256, 0, stream>>>(
                prop, pp0_w1, pp0_b1, pp_w2, pp_b2, res0_w,
                pi_w1, Ubuf, Vbuf, acc);
        } else {
            const float* pin = pbuf[(d - 1) & 1];
            fused_out_atom<<<N_ATOMS / 4, 256, 0, stream>>>(
                pin,
                out_w1 + (d - 1) * 4096, out_b1 + (d - 1) * 64,
                out_w2 + (d - 1) * 4096, out_b2 + (d - 1) * 64, out_wo + (d - 1) * 64,
                pp_w1 + (d - 1) * 4096, pp_b1 + (d - 1) * 64,
                pp_w2 + d * 4096, pp_b2 + d * 64,
                out, (d - 1) == 0 ? 1 : 0,
                pi_w1 + d * 8192, Ubuf, Vbuf, acc);
        }
        pair_kernel<<<256, 512, 0, stream>>>(
            Ubuf, Vbuf, ind2, basis,
            img2 + d * 32768, imgab + d * 16384,
            pi_b1 + d * 64, b2p + d * 256, acc);
    }
    out_kernel<<<N_ATOMS / 4, 256, 0, stream>>>(
        pbuf[(DEPTH - 1) & 1], out_w1 + (DEPTH - 1) * 4096, out_b1 + (DEPTH - 1) * 64,
        out_w2 + (DEPTH - 1) * 4096, out_b2 + (DEPTH - 1) * 64, out_wo + (DEPTH - 1) * 64,
        out, 0);
}

// Round 10
// 1030.618 us; speedup vs baseline: 1.4865x; 1.2478x over previous
//
#include <hip/hip_runtime.h>
#include <hip/hip_bf16.h>

#define N_ATOMS 25000
#define N_PAIRS 500000
#define DEPTH 4

typedef _Float16 f16x8 __attribute__((ext_vector_type(8)));
typedef float f32x16 __attribute__((ext_vector_type(16)));
typedef unsigned short u16;

__device__ __forceinline__ float tanh_fast(float x) {
    // tanh(x) = 1 - 2/(exp(2x)+1); saturates correctly at +/-inf
    float e = __expf(2.0f * x);
    return 1.0f - 2.0f * __builtin_amdgcn_rcpf(e + 1.0f);
}

__device__ __forceinline__ void split_h(float x, u16& hi, u16& lo) {
    _Float16 h = (_Float16)x;                 // RNE
    _Float16 l = (_Float16)(x - (float)h);    // residual, RNE
    hi = *(u16*)&h;
    lo = *(u16*)&l;
}

// LDS bank-swizzle on 16B-unit index (involution within 128B block).
// Verified: SQ_LDS_BANK_CONFLICT 2.02e7 -> 0 (rounds 1-3).
// Expressed via 8 precomputed bases (rb[4], wb[4]) to avoid addr-value
// register pressure (round-2 spill lesson).
__device__ __forceinline__ int swz8(int u) { return u ^ ((u >> 5) & 7); }

// ---------------- prep: split weights to hi/lo fp16, fragment-major images
// img1 per depth: [hl][ntw][ks(8)][l(64)][j(8)]        = 16384 u16
// img2 per depth: [hl][ntw][t(4)][ks(4)][l][j]         = 32768 u16  (cols permuted: n=4*ch+t)
// imgab per depth: [stage][hl][ntw][ks(4)][l][j]       = 16384 u16
__global__ __launch_bounds__(256)
void prep_kernel(const float* __restrict__ piW1, const float* __restrict__ piW2,
                 const float* __restrict__ iiW1, const float* __restrict__ iiW2,
                 u16* __restrict__ img1, u16* __restrict__ img2, u16* __restrict__ imgab) {
    int gid = blockIdx.x * 256 + threadIdx.x;     // 512 blocks * 256 = 131072 = 4*32768
    int d = gid >> 15, e = gid & 32767;
    u16 hi, lo;
    if (e < 8192) {                 // W1 [k=128][n=64]
        int k = e >> 6, n = e & 63;
        split_h(piW1[d * 8192 + e], hi, lo);
        int ntw = n >> 5, colb = n & 31;
        int ks = k >> 4, lh = (k >> 3) & 1, j = k & 7;
        int off = ((ntw * 8 + ks) * 64 + lh * 32 + colb) * 8 + j;
        img1[d * 16384 + 0 * 8192 + off] = hi;
        img1[d * 16384 + 1 * 8192 + off] = lo;
    } else if (e < 24576) {         // W2 [k=64][n=256], permuted n = 4*ch + t
        int s = e - 8192;
        int k = s >> 8, n = s & 255;
        split_h(piW2[d * 16384 + s], hi, lo);
        int ch = n >> 2, t = n & 3;
        int ntw = ch >> 5, colb = ch & 31;
        int ks = k >> 4, lh = (k >> 3) & 1, j = k & 7;
        int off = (((ntw * 4 + t) * 4 + ks) * 64 + lh * 32 + colb) * 8 + j;
        img2[d * 32768 + 0 * 16384 + off] = hi;
        img2[d * 32768 + 1 * 16384 + off] = lo;
    } else {                        // Wa (stage0) / Wb (stage1), [k=64][n=64]
        int stage = (e < 28672) ? 0 : 1;
        int s = e - (stage ? 28672 : 24576);
        int k = s >> 6, n = s & 63;
        float x = stage ? iiW2[d * 4096 + s] : iiW1[d * 4096 + s];
        split_h(x, hi, lo);
        int ntw = n >> 5, colb = n & 31;
        int ks = k >> 4, lh = (k >> 3) & 1, j = k & 7;
        int off = ((ntw * 4 + ks) * 64 + lh * 32 + colb) * 8 + j;
        imgab[d * 16384 + (stage * 2 + 0) * 4096 + off] = hi;
        imgab[d * 16384 + (stage * 2 + 1) * 4096 + off] = lo;
    }
}

__global__ __launch_bounds__(256)
void prep_b2(const float* __restrict__ piB2, float* __restrict__ b2p) {
    int d = blockIdx.x, n = threadIdx.x;
    int ch = n >> 2, t = n & 3;
    int np = (ch >> 5) * 128 + t * 32 + (ch & 31);
    b2p[d * 256 + np] = piB2[d * 256 + n];
}

// ---------------- atom-level MLP (fp32 VALU), h stored split fp16 (hi=RNE, lo=RNE(h-hi))
template <int K, bool IS_D0>
__global__ __launch_bounds__(256)
void atom_mlp(const float* __restrict__ p_in,
              const float* __restrict__ W1, const float* __restrict__ b1,
              const float* __restrict__ W2, const float* __restrict__ b2,
              const float* __restrict__ res0_w,
              _Float16* __restrict__ h_hi, _Float16* __restrict__ h_lo,
              float* __restrict__ acc_out) {
    __shared__ float sP[4][64];
    __shared__ float sH[4][64];
    int tid = threadIdx.x;
    int al = tid >> 6, c = tid & 63;
    int a = blockIdx.x * 4 + al;
    if (c < K) sP[al][c] = p_in[a * K + c];
    __syncthreads();
    float s = b1[c];
#pragma unroll
    for (int k = 0; k < K; ++k) s += sP[al][k] * W1[k * 64 + c];
    float t1 = tanh_fast(s);
    float r;
    if (IS_D0) {
        r = 0.f;
#pragma unroll
        for (int k = 0; k < 16; ++k) r += sP[al][k] * res0_w[k * 64 + c];
    } else {
        r = sP[al][c];
    }
    acc_out[a * 64 + c] = r;
    sH[al][c] = t1;
    __syncthreads();
    float s2 = b2[c];
#pragma unroll
    for (int k = 0; k < 64; ++k) s2 += sH[al][k] * W2[k * 64 + c];
    float hv = tanh_fast(s2);
    _Float16 hb = (_Float16)hv;          // RNE hi
    h_hi[a * 64 + c] = hb;
    h_lo[a * 64 + c] = (_Float16)(hv - (float)hb);
}

// ---------------- output head (fp32), standalone (after last depth)
__global__ __launch_bounds__(256)
void out_kernel(const float* __restrict__ p,
                const float* __restrict__ W1, const float* __restrict__ b1,
                const float* __restrict__ W2, const float* __restrict__ b2,
                const float* __restrict__ wo,
                float* __restrict__ out, int store) {
    __shared__ float sP[4][64];
    __shared__ float sH[4][64];
    int tid = threadIdx.x;
    int al = tid >> 6, c = tid & 63;
    int a = blockIdx.x * 4 + al;
    sP[al][c] = p[a * 64 + c];
    __syncthreads();
    float s = b1[c];
#pragma unroll
    for (int k = 0; k < 64; ++k) s += sP[al][k] * W1[k * 64 + c];
    sH[al][c] = tanh_fast(s);
    __syncthreads();
    float s2 = b2[c];
#pragma unroll
    for (int k = 0; k < 64; ++k) s2 += sH[al][k] * W2[k * 64 + c];
    float v = tanh_fast(s2) * wo[c];
#pragma unroll
    for (int off = 32; off > 0; off >>= 1) v += __shfl_down(v, off, 64);
    if (c == 0) {
        if (store) out[a] = v;
        else out[a] += v;
    }
}

// ---------------- fused: out head of depth d + atom MLP of depth d+1
// Both read the same p -> one staging pass, one launch instead of two. (R4-verified)
__global__ __launch_bounds__(256)
void fused_out_atom(const float* __restrict__ p,
                    const float* __restrict__ oW1, const float* __restrict__ ob1,
                    const float* __restrict__ oW2, const float* __restrict__ ob2,
                    const float* __restrict__ wo,
                    const float* __restrict__ aW1, const float* __restrict__ ab1,
                    const float* __restrict__ aW2, const float* __restrict__ ab2,
                    float* __restrict__ out, int store,
                    _Float16* __restrict__ h_hi, _Float16* __restrict__ h_lo,
                    float* __restrict__ acc_out) {
    __shared__ float sP[4][64];
    __shared__ float sHo[4][64];
    __shared__ float sHa[4][64];
    int tid = threadIdx.x;
    int al = tid >> 6, c = tid & 63;
    int a = blockIdx.x * 4 + al;
    float pv = p[a * 64 + c];
    sP[al][c] = pv;
    acc_out[a * 64 + c] = pv;            // residual base for next depth
    __syncthreads();
    float so = ob1[c], sa = ab1[c];
#pragma unroll
    for (int k = 0; k < 64; ++k) {
        float x = sP[al][k];
        so += x * oW1[k * 64 + c];
        sa += x * aW1[k * 64 + c];
    }
    sHo[al][c] = tanh_fast(so);
    sHa[al][c] = tanh_fast(sa);
    __syncthreads();
    float s2o = ob2[c], s2a = ab2[c];
#pragma unroll
    for (int k = 0; k < 64; ++k) {
        s2o += sHo[al][k] * oW2[k * 64 + c];
        s2a += sHa[al][k] * aW2[k * 64 + c];
    }
    float v = tanh_fast(s2o) * wo[c];
#pragma unroll
    for (int off = 32; off > 0; off >>= 1) v += __shfl_down(v, off, 64);
    if (c == 0) {
        if (store) out[a] = v;
        else out[a] += v;
    }
    float hv = tanh_fast(s2a);
    _Float16 hb = (_Float16)hv;          // RNE hi
    h_hi[a * 64 + c] = hb;
    h_lo[a * 64 + c] = (_Float16)(hv - (float)hb);
}

// ---------------- fused pair pipeline (R3-verified, 199us): fp16 MFMA 32x32x16,
// split weights + split h_i, swizzled LDS, plain __syncthreads
#define MFMA __builtin_amdgcn_mfma_f32_32x32x16_f16

__global__ __launch_bounds__(512, 2)
void pair_kernel(const _Float16* __restrict__ hhi,
                 const _Float16* __restrict__ hlo,
                 const int* __restrict__ ind2,
                 const float* __restrict__ basis,
                 const u16* __restrict__ img1,   // this depth
                 const u16* __restrict__ img2,
                 const u16* __restrict__ imgab,
                 const float* __restrict__ piB1,
                 const float* __restrict__ b2p,
                 float* __restrict__ accp) {
    __shared__ __attribute__((aligned(16))) _Float16 sW2[32768];   // 64 KB
    __shared__ __attribute__((aligned(16))) _Float16 sW1lo[8192];  // 16 KB  W1-lo frags (linear)
    __shared__ __attribute__((aligned(16))) _Float16 sA[16384];    // 32 KB  (swizzled)
    __shared__ __attribute__((aligned(16))) _Float16 sAlo[8192];   // 16 KB  (swizzled)
    __shared__ __attribute__((aligned(16))) _Float16 sPing[8192];  // 16 KB  (swizzled)
    __shared__ float sBas[128 * 4];                                //  2 KB
    __shared__ int sIdx[128];                                      // 0.5 KB
    // total 146.5 KB -> 1 block/CU, 2 waves/SIMD

    const int tid = threadIdx.x;
    for (int i = tid; i < 4096; i += 512) ((uint4*)sW2)[i] = ((const uint4*)img2)[i];
    for (int i = tid; i < 1024; i += 512) ((uint4*)sW1lo)[i] = ((const uint4*)(img1 + 8192))[i];

    const int l = tid & 63;
    const int w = tid >> 6;
    const int mt = w >> 1, ntw = w & 1;
    const int col = l & 31, kg = l >> 5;
    const int ch = ntw * 32 + col;
    const int chks = ch >> 4, chlh = (ch >> 3) & 1, chj = ch & 7;

    int rb[4], wb[4];
    {
        const int wxor = 2 * chks + chlh;
#pragma unroll
        for (int c = 0; c < 4; ++c) {
            rb[c] = (l ^ (kg + 2 * c)) << 4;
            wb[c] = (mt * 4 + chks) * 1024 + chlh * 512 + ((((c) + 4 * kg) ^ wxor) << 4) + chj * 2;
        }
    }
    const int mtsA = mt << 13;
    const int mts  = mt << 12;

    // persistent register weights: W1-hi (8 frags), ii_w1/ii_w2 hi+lo (16 frags)
    // 96 weight VGPRs + working set = 124 total, no spill at 2 waves/SIMD (R3-verified)
    f16x8 w1h[8], fa[2][4], fb[2][4];
#pragma unroll
    for (int ks = 0; ks < 8; ++ks)
        w1h[ks] = *(const f16x8*)(img1 + ntw * 4096 + ks * 512 + l * 8);
#pragma unroll
    for (int hl = 0; hl < 2; ++hl)
#pragma unroll
        for (int ks = 0; ks < 4; ++ks) {
            fa[hl][ks] = *(const f16x8*)(imgab + (0 * 2 + hl) * 4096 + ntw * 2048 + ks * 512 + l * 8);
            fb[hl][ks] = *(const f16x8*)(imgab + (1 * 2 + hl) * 4096 + ntw * 2048 + ks * 512 + l * 8);
        }
    const float b1v = piB1[ch];
    float b2v[4];
#pragma unroll
    for (int t = 0; t < 4; ++t) b2v[t] = b2p[ntw * 128 + t * 32 + col];

    const int nTiles = (N_PAIRS + 127) >> 7;

    auto gather = [&](int tile) {
        int base = tile << 7;
#pragma unroll
        for (int it = 0; it < 6; ++it) {
            int id = it * 512 + tid;
            if (id < 2048) {            // hi: both halves, K=128
                int m = id >> 4, half = (id >> 3) & 1, seg = id & 7;
                int p = base + m;
                uint4 v = make_uint4(0u, 0u, 0u, 0u);
                if (p < N_PAIRS) {
                    int row = ind2[2 * p + half];
                    v = *(const uint4*)(hhi + row * 64 + seg * 8);
                }
                int mtd = m >> 5, lrow = m & 31;
                int ks = half * 4 + (seg >> 1), lh = seg & 1;
                int u = (mtd * 8 + ks) * 64 + lh * 32 + lrow;
                *(uint4*)(sA + swz8(u) * 8) = v;
            } else {                    // lo: i-half only, K=64
                int e = id - 2048;
                int m = e >> 3, seg = e & 7;
                int p = base + m;
                uint4 v = make_uint4(0u, 0u, 0u, 0u);
                if (p < N_PAIRS) {
                    int row = ind2[2 * p];
                    v = *(const uint4*)(hlo + row * 64 + seg * 8);
                }
                int mtd = m >> 5, lrow = m & 31;
                int ks = seg >> 1, lh = seg & 1;
                int u = (mtd * 4 + ks) * 64 + lh * 32 + lrow;
                *(uint4*)(sAlo + swz8(u) * 8) = v;
            }
        }
    };
    gather(blockIdx.x);
    __syncthreads();

    for (int tile = blockIdx.x; tile < nTiles; tile += gridDim.x) {
        const int base = tile << 7;

        // ---- G1: stage basis/idx; [128x128]@[128x64]+b1, tanh -> sPing
        if (tid < 128) {
            int p = base + tid;
            float4 bv = (p < N_PAIRS) ? ((const float4*)basis)[p] : make_float4(0.f, 0.f, 0.f, 0.f);
            *(float4*)&sBas[tid * 4] = bv;
            sIdx[tid] = (p < N_PAIRS) ? ind2[2 * p] : 0;
        }
        {
            f32x16 acc = {};
            const char* blo = (const char*)(sW1lo + ntw * 4096 + l * 8);
#pragma unroll
            for (int ks = 0; ks < 8; ++ks) {
                f16x8 a = *(const f16x8*)((const char*)sA + mtsA + ks * 1024 + rb[ks & 3]);
                acc = MFMA(a, w1h[ks], acc, 0, 0, 0);
                acc = MFMA(a, *(const f16x8*)(blo + ks * 1024), acc, 0, 0, 0);
            }
#pragma unroll
            for (int ks = 0; ks < 4; ++ks) {   // h_i lo correction (i-half = k 0..63)
                f16x8 a = *(const f16x8*)((const char*)sAlo + mts + ks * 1024 + rb[ks]);
                acc = MFMA(a, w1h[ks], acc, 0, 0, 0);
            }
#pragma unroll
            for (int r = 0; r < 16; ++r)
                *(u16*)((char*)sPing + wb[r & 3] + ((r >> 2) << 7)) =
                    __builtin_bit_cast(u16, (_Float16)tanh_fast(acc[r] + b1v));
        }
        __syncthreads();

        // ---- G2: [128x64]@[64x256]+b2, tanh, in-lane basis contraction -> sA
        {
            f32x16 acc[4] = {{}, {}, {}, {}};
#pragma unroll
            for (int ks = 0; ks < 4; ++ks) {
                f16x8 a = *(const f16x8*)((const char*)sPing + mts + ks * 1024 + rb[ks]);
#pragma unroll
                for (int t = 0; t < 4; ++t) {
                    acc[t] = MFMA(a, *(const f16x8*)(sW2 + ((ntw * 4 + t) * 4 + ks) * 512 + l * 8), acc[t], 0, 0, 0);
                    acc[t] = MFMA(a, *(const f16x8*)(sW2 + 16384 + ((ntw * 4 + t) * 4 + ks) * 512 + l * 8), acc[t], 0, 0, 0);
                }
            }
#pragma unroll
            for (int r = 0; r < 16; ++r) {
                int lrow = (r & 3) + 8 * (r >> 2) + 4 * kg;
                int row = mt * 32 + lrow;
                float4 bas = *(const float4*)&sBas[row * 4];
                float s = tanh_fast(acc[0][r] + b2v[0]) * bas.x
                        + tanh_fast(acc[1][r] + b2v[1]) * bas.y
                        + tanh_fast(acc[2][r] + b2v[2]) * bas.z
                        + tanh_fast(acc[3][r] + b2v[3]) * bas.w;
                *(u16*)((char*)sA + wb[r & 3] + ((r >> 2) << 7)) =
                    __builtin_bit_cast(u16, (_Float16)s);
            }
        }
        __syncthreads();

        // ---- G3: inter @ ii_w1 (regs), tanh -> sPing
        {
            f32x16 acc = {};
#pragma unroll
            for (int ks = 0; ks < 4; ++ks) {
                f16x8 a = *(const f16x8*)((const char*)sA + mts + ks * 1024 + rb[ks]);
                acc = MFMA(a, fa[0][ks], acc, 0, 0, 0);
                acc = MFMA(a, fa[1][ks], acc, 0, 0, 0);
            }
#pragma unroll
            for (int r = 0; r < 16; ++r)
                *(u16*)((char*)sPing + wb[r & 3] + ((r >> 2) << 7)) =
                    __builtin_bit_cast(u16, (_Float16)tanh_fast(acc[r]));
        }
        __syncthreads();

        // ---- G4: @ ii_w2 (regs), tanh, atomic scatter; overlap next-tile gather
        {
            f16x8 afr[4];
#pragma unroll
            for (int ks = 0; ks < 4; ++ks)
                afr[ks] = *(const f16x8*)((const char*)sPing + mts + ks * 1024 + rb[ks]);

            gather(tile + gridDim.x);   // writes sA/sAlo only (dead until next G1)

            f32x16 acc = {};
#pragma unroll
            for (int ks = 0; ks < 4; ++ks) {
                acc = MFMA(afr[ks], fb[0][ks], acc, 0, 0, 0);
                acc = MFMA(afr[ks], fb[1][ks], acc, 0, 0, 0);
            }
#pragma unroll
            for (int r = 0; r < 16; ++r) {
                int lrow = (r & 3) + 8 * (r >> 2) + 4 * kg;
                int p = base + mt * 32 + lrow;
                if (p < N_PAIRS)
                    atomicAdd(&accp[sIdx[mt * 32 + lrow] * 64 + ch], tanh_fast(acc[r]));
            }
        }
        __syncthreads();
    }
}

extern "C" void kernel_launch(void* const* d_in, const int* in_sizes, int n_in,
                              void* d_out, int out_size, void* d_ws, size_t ws_size,
                              hipStream_t stream) {
    const int* ind2 = (const int*)d_in[0];
    const float* prop = (const float*)d_in[1];
    const float* basis = (const float*)d_in[2];
    const float* pp0_w1 = (const float*)d_in[3];
    const float* pp0_b1 = (const float*)d_in[4];
    const float* pp_w1 = (const float*)d_in[5];
    const float* pp_b1 = (const float*)d_in[6];
    const float* pp_w2 = (const float*)d_in[7];
    const float* pp_b2 = (const float*)d_in[8];
    const float* pi_w1 = (const float*)d_in[9];
    const float* pi_b1 = (const float*)d_in[10];
    const float* pi_w2 = (const float*)d_in[11];
    const float* pi_b2 = (const float*)d_in[12];
    const float* ii_w1 = (const float*)d_in[13];
    const float* ii_w2 = (const float*)d_in[14];
    const float* res0_w = (const float*)d_in[15];
    const float* out_w1 = (const float*)d_in[16];
    const float* out_b1 = (const float*)d_in[17];
    const float* out_w2 = (const float*)d_in[18];
    const float* out_b2 = (const float*)d_in[19];
    const float* out_wo = (const float*)d_in[20];
    float* out = (float*)d_out;

    // workspace layout
    float* B0 = (float*)d_ws;                            // 25000*64 f32
    float* B1 = B0 + N_ATOMS * 64;                       // 25000*64 f32
    _Float16* Hhi = (_Float16*)(B1 + N_ATOMS * 64);      // 25000*64 f16
    _Float16* Hlo = Hhi + N_ATOMS * 64;                  // 25000*64 f16
    u16* img1 = (u16*)(Hlo + N_ATOMS * 64);              // 4*16384 u16
    u16* img2 = img1 + 4 * 16384;                        // 4*32768 u16
    u16* imgab = img2 + 4 * 32768;                       // 4*16384 u16
    float* b2p = (float*)(imgab + 4 * 16384);            // 4*256 f32
    float* pbuf[2] = {B0, B1};

    prep_kernel<<<512, 256, 0, stream>>>(pi_w1, pi_w2, ii_w1, ii_w2, img1, img2, imgab);
    prep_b2<<<4, 256, 0, stream>>>(pi_b2, b2p);

    for (int d = 0; d < DEPTH; ++d) {
        float* acc = pbuf[d & 1];
        if (d == 0) {
            atom_mlp<16, true><<<N_ATOMS / 4, 256, 0, stream>>>(
                prop, pp0_w1, pp0_b1, pp_w2, pp_b2, res0_w, Hhi, Hlo, acc);
        } else {
            // fused: out head of depth d-1 + atom MLP of depth d
            const float* pin = pbuf[(d - 1) & 1];
            fused_out_atom<<<N_ATOMS / 4, 256, 0, stream>>>(
                pin,
                out_w1 + (d - 1) * 4096, out_b1 + (d - 1) * 64,
                out_w2 + (d - 1) * 4096, out_b2 + (d - 1) * 64, out_wo + (d - 1) * 64,
                pp_w1 + (d - 1) * 4096, pp_b1 + (d - 1) * 64,
                pp_w2 + d * 4096, pp_b2 + d * 64,
                out, (d - 1) == 0 ? 1 : 0,
                Hhi, Hlo, acc);
        }
        pair_kernel<<<256, 512, 0, stream>>>(
            Hhi, Hlo, ind2, basis,
            img1 + d * 16384, img2 + d * 32768, imgab + d * 16384,
            pi_b1 + d * 64, b2p + d * 256, acc);
    }
    out_kernel<<<N_ATOMS / 4, 256, 0, stream>>>(
        pbuf[(DEPTH - 1) & 1], out_w1 + (DEPTH - 1) * 4096, out_b1 + (DEPTH - 1) * 64,
        out_w2 + (DEPTH - 1) * 4096, out_b2 + (DEPTH - 1) * 64, out_wo + (DEPTH - 1) * 64,
        out, 0);
}